// Round 12
// baseline (125.874 us; speedup 1.0000x reference)
//
#include <hip/hip_runtime.h>
#include <hip/hip_bf16.h>

typedef __attribute__((ext_vector_type(8))) short short8;
typedef __attribute__((ext_vector_type(4))) float f32x4;

#define B_  4
#define H_  16
#define T_  4096
#define D_  128
#define BS_ 32
#define C_  128
#define BH_ (B_ * H_)

// d-permutation making each MFMA fragment's 8 bf16 contiguous (16B):
// pos = chunk32*32 + q4*8 + half16*4 + low2   where d = chunk32*32 + half16*16 + q4*4 + low2
// Aligned quads are preserved: posperm(4l+i) = posperm(4l) + i, i in 0..3.
__device__ __forceinline__ int posperm(int x) {
  return (x & ~31) | (((x >> 2) & 3) << 3) | (((x >> 4) & 1) << 2) | (x & 3);
}

__device__ __forceinline__ unsigned short f2bf(float f) {
  __hip_bfloat16 h = __float2bfloat16(f);
  return __builtin_bit_cast(unsigned short, h);
}

__device__ __forceinline__ void gload_lds16(const uint4* g, uint4* l) {
  __builtin_amdgcn_global_load_lds(
      (const __attribute__((address_space(1))) unsigned int*)g,
      (__attribute__((address_space(3))) unsigned int*)l, 16, 0, 0);
}

// ---------------- compress: mean-pool k,v -> bf16 k_cmp [C][D] (x 1/sqrt(d)), vT [D][C] ----
// Element at row r, position p stored at ushort index r*128 + (posperm(p) ^ ((r&7)<<3)).
// vT path: v-means bounce through a 4KB LDS tile so the transposed store is
// emitted as uint2 (8B) runs — posperm maps 4 consecutive cb to 4 contiguous
// ushorts and the XOR only touches bits 3..5, so (pos0 ^ x) + j is exact.
__global__ __launch_bounds__(256) void compress_kernel(
    const float* __restrict__ k, const float* __restrict__ v,
    unsigned short* __restrict__ kc, unsigned short* __restrict__ vT) {
  __shared__ float vls[8 * 128];  // [cb_local][d]
  int blk = blockIdx.x;
  int bh  = blk >> 4;
  int cg  = blk & 15;
  int cbl = threadIdx.x >> 5;             // local c-block 0..7
  int cb  = cg * 8 + cbl;                 // c-block index 0..127
  int l   = threadIdx.x & 31;             // d-quad index
  const float* kp = k + ((size_t)bh * T_ + (size_t)cb * BS_) * D_ + 4 * l;
  const float* vp = v + ((size_t)bh * T_ + (size_t)cb * BS_) * D_ + 4 * l;
  f32x4 ks = {0.f, 0.f, 0.f, 0.f}, vs = {0.f, 0.f, 0.f, 0.f};
#pragma unroll
  for (int j = 0; j < BS_; ++j) {
    f32x4 a = __builtin_nontemporal_load((const f32x4*)(kp + (size_t)j * D_));
    f32x4 b = __builtin_nontemporal_load((const f32x4*)(vp + (size_t)j * D_));
    ks += a;
    vs += b;
  }
  const float s  = 1.0f / BS_;
  const float sk = s * 0.08838834764831845f;  // fold 1/sqrt(128) into K
  size_t slab = (size_t)bh * (C_ * D_);
  unsigned short kq[4] = {f2bf(ks[0] * sk), f2bf(ks[1] * sk), f2bf(ks[2] * sk), f2bf(ks[3] * sk)};
  int p0 = posperm(4 * l) ^ ((cb & 7) << 3);
  *(uint2*)&kc[slab + (size_t)cb * D_ + p0] = *(const uint2*)kq;

  // v means -> LDS (f32x4, conflict-free)
  *(f32x4*)&vls[cbl * 128 + 4 * l] = vs * s;
  __syncthreads();

  // transposed vT store: thread = (row d, run); one uint2 of 4 bf16
  int d   = threadIdx.x >> 1;
  int run = threadIdx.x & 1;
  unsigned short vq[4];
#pragma unroll
  for (int j = 0; j < 4; ++j) vq[j] = f2bf(vls[(run * 4 + j) * 128 + d]);
  int posr = posperm(cg * 8 + run * 4) ^ ((d & 7) << 3);
  *(uint2*)&vT[slab + (size_t)d * C_ + posr] = *(const uint2*)vq;
}

// ---------------- attention over compressed KV ----------------
// Per WG: one head, 64 q-rows (4 waves x 16 rows), 256 threads, LDS 32 KB.
// Order: bounce writes -> pf pack -> bounce reads -> lgkmcnt(0) -> issue
// wave-private vT gloads -> nt score stores -> vmcnt(8) [gloads retired,
// stores IN FLIGHT] -> s_barrier -> PV -> sync -> out bounce.
__global__ __launch_bounds__(256, 5) void attn_kernel(
    const float* __restrict__ q, const unsigned short* __restrict__ kc,
    const unsigned short* __restrict__ vT, float* __restrict__ out,
    float* __restrict__ score) {
  __shared__ uint4 sbuf[2048];  // 32 KB, time-shared kc -> bounce -> vT

  int blk    = blockIdx.x;
  int bh     = blk >> 6;
  int tchunk = blk & 63;
  int tid    = threadIdx.x;
  int wave   = tid >> 6;
  int lane   = tid & 63;
  int g      = lane >> 4;
  int lr     = lane & 15;
  int rx     = lr & 7;
  int t0     = tchunk * 64 + wave * 16;  // wave's 16 q-rows

  const uint4* kg = (const uint4*)(kc + (size_t)bh * (C_ * D_));
  const uint4* vg = (const uint4*)(vT + (size_t)bh * (C_ * D_));

  // q loads first (oldest in vmem queue; HBM latency hides under kc stage)
  const float* qrow = q + ((size_t)bh * T_ + t0 + lr) * D_;
  f32x4 qa[4], qb[4];
#pragma unroll
  for (int ks = 0; ks < 4; ++ks) {
    int d0 = 4 * g + 32 * ks;
    qa[ks] = __builtin_nontemporal_load((const f32x4*)(qrow + d0));
    qb[ks] = __builtin_nontemporal_load((const f32x4*)(qrow + d0 + 16));
  }

  // stage kc via async global->LDS
#pragma unroll
  for (int it = 0; it < 8; ++it) gload_lds16(&kg[it * 256 + tid], &sbuf[it * 256 + tid]);

  // Q fragments (B operand): lane holds Q[t0+lr][d = 4g+(i&3)+16(i>>2)+32ks]
  short8 qf[4];
#pragma unroll
  for (int ks = 0; ks < 4; ++ks) {
    short8 f;
    f[0] = (short)f2bf(qa[ks][0]); f[1] = (short)f2bf(qa[ks][1]);
    f[2] = (short)f2bf(qa[ks][2]); f[3] = (short)f2bf(qa[ks][3]);
    f[4] = (short)f2bf(qb[ks][0]); f[5] = (short)f2bf(qb[ks][1]);
    f[6] = (short)f2bf(qb[ks][2]); f[7] = (short)f2bf(qb[ks][3]);
    qf[ks] = f;
  }
  __syncthreads();  // sync1: kc staged (drains vmcnt incl. global_load_lds)

  // QK^T: accS[cm] = S^T[c = 4g+r+16cm][t = t0+lr]
  f32x4 accS[8];
#pragma unroll
  for (int cm = 0; cm < 8; ++cm) accS[cm] = f32x4{0.f, 0.f, 0.f, 0.f};
#pragma unroll
  for (int cm = 0; cm < 8; ++cm) {
    int rbase = (lr + 16 * cm) * 16;
#pragma unroll
    for (int ks = 0; ks < 4; ++ks) {
      uint4 kf = sbuf[rbase + ((4 * ks + g) ^ rx)];
      accS[cm] = __builtin_amdgcn_mfma_f32_16x16x32_bf16(
          __builtin_bit_cast(short8, kf), qf[ks], accS[cm], 0, 0, 0);
    }
  }

  // softmax over c (row t = t0+lr spread across lane-groups g)
  float m = -3.0e38f;
#pragma unroll
  for (int cm = 0; cm < 8; ++cm)
#pragma unroll
    for (int r = 0; r < 4; ++r) m = fmaxf(m, accS[cm][r]);
  m = fmaxf(m, __shfl_xor(m, 16));
  m = fmaxf(m, __shfl_xor(m, 32));

  float sum = 0.f;
#pragma unroll
  for (int cm = 0; cm < 8; ++cm) {
#pragma unroll
    for (int r = 0; r < 4; ++r) {
      float p = __expf(accS[cm][r] - m);
      accS[cm][r] = p;
      sum += p;
    }
  }
  sum += __shfl_xor(sum, 16);
  sum += __shfl_xor(sum, 32);
  float inv = 1.0f / sum;
#pragma unroll
  for (int cm = 0; cm < 8; ++cm)
#pragma unroll
    for (int r = 0; r < 4; ++r) accS[cm][r] *= inv;

  __syncthreads();  // sync2: kc dead everywhere -> sbuf reusable as bounce

  // ---- score bounce writes (wave-private 8 KB) ----
  float* bw = (float*)sbuf + wave * 2048;
#pragma unroll
  for (int cm = 0; cm < 8; ++cm) {
    int c4 = (g + 4 * cm) ^ rx;
    *(f32x4*)&bw[lr * 128 + c4 * 4] = accS[cm];
  }

  // pf: P^T fragments (k over c) — packed NOW so accS dies before valS lives
  short8 pf[4];
#pragma unroll
  for (int ks = 0; ks < 4; ++ks) {
    short8 f;
#pragma unroll
    for (int r = 0; r < 4; ++r) {
      f[r]     = (short)f2bf(accS[2 * ks][r]);
      f[4 + r] = (short)f2bf(accS[2 * ks + 1][r]);
    }
    pf[ks] = f;
  }

  // bounce reads (valS) — accS no longer live
  f32x4 valS[8];
#pragma unroll
  for (int j = 0; j < 8; ++j) {
    int row = 2 * j + (lane >> 5);
    int c4  = lane & 31;
    valS[j] = *(const f32x4*)&bw[row * 128 + (c4 ^ (row & 7)) * 4];
  }
  // my bounce reads complete before my gloads may overwrite my region
  asm volatile("s_waitcnt lgkmcnt(0)" ::: "memory");
  __builtin_amdgcn_sched_barrier(0);

  // issue vT re-stage, wave-private quarter (8 OLDEST vmem ops); identity map:
  // wave w covers uint4 indices [w*512, (w+1)*512) = exactly its bounce region
  {
    int base0 = wave * 512 + lane;
#pragma unroll
    for (int it = 0; it < 8; ++it)
      gload_lds16(&vg[base0 + it * 64], &sbuf[base0 + it * 64]);
  }
  __builtin_amdgcn_sched_barrier(0);

  // nt score stores (8 NEWEST vmem ops; drain under PV)
  float* dstS = score + ((size_t)bh * T_ + t0) * C_;
#pragma unroll
  for (int j = 0; j < 8; ++j) {
    int row = 2 * j + (lane >> 5);
    int c4  = lane & 31;
    __builtin_nontemporal_store(valS[j], (f32x4*)&dstS[(size_t)row * C_ + c4 * 4]);
  }
  __builtin_amdgcn_sched_barrier(0);
  // wait only the 8 vT gloads (in-order retire); score stores stay in flight
  asm volatile("s_waitcnt vmcnt(8) lgkmcnt(0)" ::: "memory");
  __builtin_amdgcn_s_barrier();  // sync3: vT fully resident
  __builtin_amdgcn_sched_barrier(0);

  // PV as O^T: o[nt] = O^T[d = 4g+r+16nt][t0+lr], B-fragments from LDS
  f32x4 o[8];
#pragma unroll
  for (int nt = 0; nt < 8; ++nt) o[nt] = f32x4{0.f, 0.f, 0.f, 0.f};
#pragma unroll
  for (int nt = 0; nt < 8; ++nt) {
    int rbase = (lr + 16 * nt) * 16;
#pragma unroll
    for (int ks = 0; ks < 4; ++ks) {
      uint4 vf = sbuf[rbase + ((4 * ks + g) ^ rx)];
      o[nt] = __builtin_amdgcn_mfma_f32_16x16x32_bf16(
          __builtin_bit_cast(short8, vf), pf[ks], o[nt], 0, 0, 0);
    }
  }
  __syncthreads();  // sync4: all waves done reading vT -> region reusable

  // ---- out bounce + nt coalesced stores ----
#pragma unroll
  for (int nt = 0; nt < 8; ++nt) {
    int c4 = (g + 4 * nt) ^ rx;
    *(f32x4*)&bw[lr * 128 + c4 * 4] = o[nt];
  }
  float* dstO = out + ((size_t)bh * T_ + t0) * D_;
#pragma unroll
  for (int j = 0; j < 8; ++j) {
    int row = 2 * j + (lane >> 5);
    int c4  = lane & 31;
    f32x4 val = *(const f32x4*)&bw[row * 128 + (c4 ^ (row & 7)) * 4];
    __builtin_nontemporal_store(val, (f32x4*)&dstO[(size_t)row * D_ + c4 * 4]);
  }
}

extern "C" void kernel_launch(void* const* d_in, const int* in_sizes, int n_in,
                              void* d_out, int out_size, void* d_ws, size_t ws_size,
                              hipStream_t stream) {
  const float* q = (const float*)d_in[0];
  const float* k = (const float*)d_in[1];
  const float* v = (const float*)d_in[2];
  float* out   = (float*)d_out;
  float* score = out + (size_t)BH_ * T_ * D_;

  unsigned short* kc = (unsigned short*)d_ws;       // 2 MB
  unsigned short* vT = kc + (size_t)BH_ * C_ * D_;  // 2 MB

  compress_kernel<<<BH_ * 16, 256, 0, stream>>>(k, v, kc, vT);
  attn_kernel<<<BH_ * 64, 256, 0, stream>>>(q, kc, vT, out, score);
}

// Round 14
// 125.465 us; speedup vs baseline: 1.0033x; 1.0033x over previous
//
#include <hip/hip_runtime.h>
#include <hip/hip_bf16.h>

typedef __attribute__((ext_vector_type(8))) short short8;
typedef __attribute__((ext_vector_type(4))) float f32x4;

#define B_  4
#define H_  16
#define T_  4096
#define D_  128
#define BS_ 32
#define C_  128
#define BH_ (B_ * H_)

// d-permutation making each MFMA fragment's 8 bf16 contiguous (16B):
// pos = chunk32*32 + q4*8 + half16*4 + low2   where d = chunk32*32 + half16*16 + q4*4 + low2
// Aligned quads are preserved: posperm(4l+i) = posperm(4l) + i, i in 0..3.
__device__ __forceinline__ int posperm(int x) {
  return (x & ~31) | (((x >> 2) & 3) << 3) | (((x >> 4) & 1) << 2) | (x & 3);
}

__device__ __forceinline__ unsigned short f2bf(float f) {
  __hip_bfloat16 h = __float2bfloat16(f);
  return __builtin_bit_cast(unsigned short, h);
}

__device__ __forceinline__ void gload_lds16(const uint4* g, uint4* l) {
  __builtin_amdgcn_global_load_lds(
      (const __attribute__((address_space(1))) unsigned int*)g,
      (__attribute__((address_space(3))) unsigned int*)l, 16, 0, 0);
}

// ---------------- compress: mean-pool k,v -> bf16 k_cmp [C][D] (x 1/sqrt(d)), vT [D][C] ----
// Element at row r, position p stored at ushort index r*128 + (posperm(p) ^ ((r&7)<<3)).
__global__ __launch_bounds__(256) void compress_kernel(
    const float* __restrict__ k, const float* __restrict__ v,
    unsigned short* __restrict__ kc, unsigned short* __restrict__ vT) {
  int blk = blockIdx.x;
  int bh  = blk >> 4;
  int cg  = blk & 15;
  int cb  = cg * 8 + (threadIdx.x >> 5);  // c-block index 0..127
  int l   = threadIdx.x & 31;             // d-quad index
  const float* kp = k + ((size_t)bh * T_ + (size_t)cb * BS_) * D_ + 4 * l;
  const float* vp = v + ((size_t)bh * T_ + (size_t)cb * BS_) * D_ + 4 * l;
  float4 ks = {0.f, 0.f, 0.f, 0.f}, vs = {0.f, 0.f, 0.f, 0.f};
#pragma unroll
  for (int j = 0; j < BS_; ++j) {
    float4 a = *(const float4*)(kp + (size_t)j * D_);
    float4 b = *(const float4*)(vp + (size_t)j * D_);
    ks.x += a.x; ks.y += a.y; ks.z += a.z; ks.w += a.w;
    vs.x += b.x; vs.y += b.y; vs.z += b.z; vs.w += b.w;
  }
  const float s  = 1.0f / BS_;
  const float sk = s * 0.08838834764831845f;  // fold 1/sqrt(128) into K
  size_t slab = (size_t)bh * (C_ * D_);
  unsigned short kq[4] = {f2bf(ks.x * sk), f2bf(ks.y * sk), f2bf(ks.z * sk), f2bf(ks.w * sk)};
  int p0 = posperm(4 * l) ^ ((cb & 7) << 3);
  *(uint2*)&kc[slab + (size_t)cb * D_ + p0] = *(const uint2*)kq;
  float vv[4] = {vs.x * s, vs.y * s, vs.z * s, vs.w * s};
#pragma unroll
  for (int i = 0; i < 4; ++i) {
    int d = 4 * l + i;
    vT[slab + (size_t)d * C_ + (posperm(cb) ^ ((d & 7) << 3))] = f2bf(vv[i]);
  }
}

// ---------------- attention over compressed KV ----------------
// Per WG: one head, 64 q-rows (4 waves x 16 rows), 256 threads, LDS 32 KB.
// Order: bounce writes -> pf pack -> bounce reads -> lgkmcnt(0) -> issue
// wave-private vT gloads -> nt score stores -> vmcnt(8) [gloads retired,
// stores IN FLIGHT] -> s_barrier -> PV -> sync -> out bounce.
__global__ __launch_bounds__(256, 5) void attn_kernel(
    const float* __restrict__ q, const unsigned short* __restrict__ kc,
    const unsigned short* __restrict__ vT, float* __restrict__ out,
    float* __restrict__ score) {
  __shared__ uint4 sbuf[2048];  // 32 KB, time-shared kc -> bounce -> vT

  int blk    = blockIdx.x;
  int bh     = blk >> 6;
  int tchunk = blk & 63;
  int tid    = threadIdx.x;
  int wave   = tid >> 6;
  int lane   = tid & 63;
  int g      = lane >> 4;
  int lr     = lane & 15;
  int rx     = lr & 7;
  int t0     = tchunk * 64 + wave * 16;  // wave's 16 q-rows

  const uint4* kg = (const uint4*)(kc + (size_t)bh * (C_ * D_));
  const uint4* vg = (const uint4*)(vT + (size_t)bh * (C_ * D_));

  // q loads first (oldest in vmem queue; HBM latency hides under kc stage)
  const float* qrow = q + ((size_t)bh * T_ + t0 + lr) * D_;
  float4 qa[4], qb[4];
#pragma unroll
  for (int ks = 0; ks < 4; ++ks) {
    int d0 = 4 * g + 32 * ks;
    qa[ks] = *(const float4*)(qrow + d0);
    qb[ks] = *(const float4*)(qrow + d0 + 16);
  }

  // stage kc via async global->LDS
#pragma unroll
  for (int it = 0; it < 8; ++it) gload_lds16(&kg[it * 256 + tid], &sbuf[it * 256 + tid]);

  // Q fragments (B operand): lane holds Q[t0+lr][d = 4g+(i&3)+16(i>>2)+32ks]
  short8 qf[4];
#pragma unroll
  for (int ks = 0; ks < 4; ++ks) {
    short8 f;
    f[0] = (short)f2bf(qa[ks].x); f[1] = (short)f2bf(qa[ks].y);
    f[2] = (short)f2bf(qa[ks].z); f[3] = (short)f2bf(qa[ks].w);
    f[4] = (short)f2bf(qb[ks].x); f[5] = (short)f2bf(qb[ks].y);
    f[6] = (short)f2bf(qb[ks].z); f[7] = (short)f2bf(qb[ks].w);
    qf[ks] = f;
  }
  __syncthreads();  // sync1: kc staged (drains vmcnt incl. global_load_lds)

  // QK^T: accS[cm] = S^T[c = 4g+r+16cm][t = t0+lr]
  f32x4 accS[8];
#pragma unroll
  for (int cm = 0; cm < 8; ++cm) accS[cm] = f32x4{0.f, 0.f, 0.f, 0.f};
#pragma unroll
  for (int cm = 0; cm < 8; ++cm) {
    int rbase = (lr + 16 * cm) * 16;
#pragma unroll
    for (int ks = 0; ks < 4; ++ks) {
      uint4 kf = sbuf[rbase + ((4 * ks + g) ^ rx)];
      accS[cm] = __builtin_amdgcn_mfma_f32_16x16x32_bf16(
          __builtin_bit_cast(short8, kf), qf[ks], accS[cm], 0, 0, 0);
    }
  }

  // softmax over c (row t = t0+lr spread across lane-groups g)
  float m = -3.0e38f;
#pragma unroll
  for (int cm = 0; cm < 8; ++cm)
#pragma unroll
    for (int r = 0; r < 4; ++r) m = fmaxf(m, accS[cm][r]);
  m = fmaxf(m, __shfl_xor(m, 16));
  m = fmaxf(m, __shfl_xor(m, 32));

  float sum = 0.f;
#pragma unroll
  for (int cm = 0; cm < 8; ++cm) {
#pragma unroll
    for (int r = 0; r < 4; ++r) {
      float p = __expf(accS[cm][r] - m);
      accS[cm][r] = p;
      sum += p;
    }
  }
  sum += __shfl_xor(sum, 16);
  sum += __shfl_xor(sum, 32);
  float inv = 1.0f / sum;
#pragma unroll
  for (int cm = 0; cm < 8; ++cm)
#pragma unroll
    for (int r = 0; r < 4; ++r) accS[cm][r] *= inv;

  __syncthreads();  // sync2: kc dead everywhere -> sbuf reusable as bounce

  // ---- score bounce writes (wave-private 8 KB); accS's last use is here+pf ----
  float* bw = (float*)sbuf + wave * 2048;
#pragma unroll
  for (int cm = 0; cm < 8; ++cm) {
    int c4 = (g + 4 * cm) ^ rx;
    *(f32x4*)&bw[lr * 128 + c4 * 4] = accS[cm];
  }

  // pf: P^T fragments (k over c) — packed NOW so accS dies before valS lives
  short8 pf[4];
#pragma unroll
  for (int ks = 0; ks < 4; ++ks) {
    short8 f;
#pragma unroll
    for (int r = 0; r < 4; ++r) {
      f[r]     = (short)f2bf(accS[2 * ks][r]);
      f[4 + r] = (short)f2bf(accS[2 * ks + 1][r]);
    }
    pf[ks] = f;
  }

  // bounce reads (valS) — accS no longer live
  f32x4 valS[8];
#pragma unroll
  for (int j = 0; j < 8; ++j) {
    int row = 2 * j + (lane >> 5);
    int c4  = lane & 31;
    valS[j] = *(const f32x4*)&bw[row * 128 + (c4 ^ (row & 7)) * 4];
  }
  // my bounce reads complete before my gloads may overwrite my region
  asm volatile("s_waitcnt lgkmcnt(0)" ::: "memory");
  __builtin_amdgcn_sched_barrier(0);

  // issue vT re-stage, wave-private quarter (8 OLDEST vmem ops); identity map:
  // wave w covers uint4 indices [w*512, (w+1)*512) = exactly its bounce region
  {
    int base0 = wave * 512 + lane;
#pragma unroll
    for (int it = 0; it < 8; ++it)
      gload_lds16(&vg[base0 + it * 64], &sbuf[base0 + it * 64]);
  }
  __builtin_amdgcn_sched_barrier(0);

  // nt score stores (8 NEWEST vmem ops; drain under PV)
  float* dstS = score + ((size_t)bh * T_ + t0) * C_;
#pragma unroll
  for (int j = 0; j < 8; ++j) {
    int row = 2 * j + (lane >> 5);
    int c4  = lane & 31;
    __builtin_nontemporal_store(valS[j], (f32x4*)&dstS[(size_t)row * C_ + c4 * 4]);
  }
  __builtin_amdgcn_sched_barrier(0);
  // wait only the 8 vT gloads (in-order retire); score stores stay in flight
  asm volatile("s_waitcnt vmcnt(8) lgkmcnt(0)" ::: "memory");
  __builtin_amdgcn_s_barrier();  // sync3: vT fully resident
  __builtin_amdgcn_sched_barrier(0);

  // PV as O^T: o[nt] = O^T[d = 4g+r+16nt][t0+lr], B-fragments from LDS
  f32x4 o[8];
#pragma unroll
  for (int nt = 0; nt < 8; ++nt) o[nt] = f32x4{0.f, 0.f, 0.f, 0.f};
#pragma unroll
  for (int nt = 0; nt < 8; ++nt) {
    int rbase = (lr + 16 * nt) * 16;
#pragma unroll
    for (int ks = 0; ks < 4; ++ks) {
      uint4 vf = sbuf[rbase + ((4 * ks + g) ^ rx)];
      o[nt] = __builtin_amdgcn_mfma_f32_16x16x32_bf16(
          __builtin_bit_cast(short8, vf), pf[ks], o[nt], 0, 0, 0);
    }
  }
  __syncthreads();  // sync4: all waves done reading vT -> region reusable

  // ---- out bounce + nt coalesced stores ----
#pragma unroll
  for (int nt = 0; nt < 8; ++nt) {
    int c4 = (g + 4 * nt) ^ rx;
    *(f32x4*)&bw[lr * 128 + c4 * 4] = o[nt];
  }
  float* dstO = out + ((size_t)bh * T_ + t0) * D_;
#pragma unroll
  for (int j = 0; j < 8; ++j) {
    int row = 2 * j + (lane >> 5);
    int c4  = lane & 31;
    f32x4 val = *(const f32x4*)&bw[row * 128 + (c4 ^ (row & 7)) * 4];
    __builtin_nontemporal_store(val, (f32x4*)&dstO[(size_t)row * D_ + c4 * 4]);
  }
}

extern "C" void kernel_launch(void* const* d_in, const int* in_sizes, int n_in,
                              void* d_out, int out_size, void* d_ws, size_t ws_size,
                              hipStream_t stream) {
  const float* q = (const float*)d_in[0];
  const float* k = (const float*)d_in[1];
  const float* v = (const float*)d_in[2];
  float* out   = (float*)d_out;
  float* score = out + (size_t)BH_ * T_ * D_;

  unsigned short* kc = (unsigned short*)d_ws;       // 2 MB
  unsigned short* vT = kc + (size_t)BH_ * C_ * D_;  // 2 MB

  compress_kernel<<<BH_ * 16, 256, 0, stream>>>(k, v, kc, vT);
  attn_kernel<<<BH_ * 64, 256, 0, stream>>>(q, kc, vT, out, score);
}